// Round 3
// baseline (175.201 us; speedup 1.0000x reference)
//
#include <hip/hip_runtime.h>
#include <hip/hip_bf16.h>

// Problem constants (from reference)
#define V 50000
#define D 128
#define B 2048
#define P 20

// Stage-1 GEMM tiling: x[B][D] = inputs[B][V] @ W_emb[D][V]^T, split-K
#define BM 128
#define BN 128                  // == D, whole N in one tile
#define BK 64
#define NSPLIT 56               // 8 XCDs x 7 splits
#define KC 896                  // K-range per split (multiple of BK)
#define NMT (B / BM)            // 16 m-tiles

typedef float  f32x4   __attribute__((ext_vector_type(4)));
typedef short  bf16x8  __attribute__((ext_vector_type(8)));
typedef unsigned int uint4v __attribute__((ext_vector_type(4)));

// truncating fp32->bf16 pack of two floats into one u32 (low = a, high = b)
__device__ __forceinline__ unsigned int pk2(float a, float b) {
    return (__float_as_uint(b) & 0xFFFF0000u) | (__float_as_uint(a) >> 16);
}
// RNE fp32->bf16 (used for part partials)
__device__ __forceinline__ unsigned short f2bf(float f) {
    unsigned int u = __float_as_uint(f);
    return (unsigned short)((u + 0x7FFFu + ((u >> 16) & 1u)) >> 16);
}

// ---------------- stage 1: split-K bf16 MFMA GEMM ----------------
__global__ __launch_bounds__(256, 4)
void w2v_gemm_splitk(const float* __restrict__ Ain, const float* __restrict__ Wemb,
                     void* __restrict__ part, int use_atomic) {
    // one 32 KB LDS pool: As = [0,16K), Ws = [16K,32K); reused as C-tile in epilogue
    __shared__ unsigned short Sm[2 * BM * BK];
    unsigned short* As = Sm;
    unsigned short* Ws = Sm + BM * BK;

    // XCD-aware mapping: all 16 m-tiles of a split on one XCD (i%8 heuristic)
    const int i     = blockIdx.x;          // 0..895
    const int xcd   = i & 7;
    const int j     = i >> 3;              // 0..111
    const int s     = xcd * 7 + (j >> 4);  // 0..55  (7 splits per XCD)
    const int mtile = j & 15;
    const int m0    = mtile * BM;
    const int k0    = s * KC;
    const int k1    = (k0 + KC < V) ? (k0 + KC) : V;   // V%8==0 -> k1%8==0

    const int tid  = threadIdx.x;
    const int lane = tid & 63;
    const int wid  = tid >> 6;
    const int wr   = wid >> 1;             // wave row (0..1) -> 64 rows
    const int wc   = wid & 1;              // wave col (0..1) -> 64 cols

    f32x4 acc[4][4] = {};

    for (int ks = k0; ks < k1; ks += BK) {
        // ---- stage A(128x64) and W(128x64) fp32 -> bf16 into swizzled LDS ----
        // slot covers 8 k's (16B bf16). 1024 slots per matrix, 4 iters each.
#pragma unroll
        for (int t = 0; t < 8; ++t) {
            const int slot = tid + (t & 3) * 256;   // 0..1023
            const int row  = slot >> 3;
            const int c8   = slot & 7;
            const int kg   = ks + c8 * 8;
            f32x4 v0 = {0.f, 0.f, 0.f, 0.f};
            f32x4 v1 = {0.f, 0.f, 0.f, 0.f};
            if (kg < k1) {   // kg%8==0, k1%8==0 -> full 8 valid
                if (t < 4) { // A: strictly read-once -> non-temporal, keep out of L2
                    const f32x4* src = reinterpret_cast<const f32x4*>(&Ain[(size_t)(m0 + row) * V + kg]);
                    v0 = __builtin_nontemporal_load(src);
                    v1 = __builtin_nontemporal_load(src + 1);
                } else {     // W: reused by 16 blocks on this XCD -> cached
                    const f32x4* src = reinterpret_cast<const f32x4*>(&Wemb[(size_t)row * V + kg]);
                    v0 = src[0];
                    v1 = src[1];
                }
            }
            uint4v u;
            u.x = pk2(v0[0], v0[1]);
            u.y = pk2(v0[2], v0[3]);
            u.z = pk2(v1[0], v1[1]);
            u.w = pk2(v1[2], v1[3]);
            const unsigned dst = (unsigned)(row * 128) + (((unsigned)(c8 * 16)) ^ ((unsigned)(row & 7) << 4));
            char* base = (t < 4) ? (char*)As : (char*)Ws;
            *reinterpret_cast<uint4v*>(base + dst) = u;
        }
        __syncthreads();

        // ---- MFMA inner loop ----
#pragma unroll
        for (int kk = 0; kk < BK; kk += 32) {
            const unsigned kb = (unsigned)(kk * 2) + ((unsigned)(lane >> 4) << 4); // byte offset of 8-k group
            bf16x8 af[4], wf[4];
#pragma unroll
            for (int m = 0; m < 4; ++m) {
                const int r = wr * 64 + m * 16 + (lane & 15);
                af[m] = *reinterpret_cast<const bf16x8*>((char*)As + r * 128 + (kb ^ ((unsigned)(r & 7) << 4)));
            }
#pragma unroll
            for (int n = 0; n < 4; ++n) {
                const int r = wc * 64 + n * 16 + (lane & 15);
                wf[n] = *reinterpret_cast<const bf16x8*>((char*)Ws + r * 128 + (kb ^ ((unsigned)(r & 7) << 4)));
            }
#pragma unroll
            for (int m = 0; m < 4; ++m)
#pragma unroll
                for (int n = 0; n < 4; ++n)
                    acc[m][n] = __builtin_amdgcn_mfma_f32_16x16x32_bf16(af[m], wf[n], acc[m][n], 0, 0, 0);
        }
        __syncthreads();
    }

    // ---- epilogue ----
    if (use_atomic) {
        // fallback: fp32 atomic accumulate into part[B][D]
        float* outp = (float*)part;
#pragma unroll
        for (int m = 0; m < 4; ++m) {
            int r0 = m0 + wr * 64 + m * 16 + (lane >> 4) * 4;
#pragma unroll
            for (int n = 0; n < 4; ++n) {
                int c0 = wc * 64 + n * 16 + (lane & 15);
#pragma unroll
                for (int jj = 0; jj < 4; ++jj)
                    atomicAdd(&outp[(size_t)(r0 + jj) * D + c0], acc[m][n][jj]);
            }
        }
        return;
    }
    // bf16 part: transpose acc through LDS (Sm now free), stream 32 KB coalesced + non-temporal
#pragma unroll
    for (int m = 0; m < 4; ++m) {
        int r0 = wr * 64 + m * 16 + (lane >> 4) * 4;
#pragma unroll
        for (int n = 0; n < 4; ++n) {
            int c0 = wc * 64 + n * 16 + (lane & 15);
#pragma unroll
            for (int jj = 0; jj < 4; ++jj)
                Sm[(r0 + jj) * 128 + c0] = f2bf(acc[m][n][jj]);
        }
    }
    __syncthreads();
    char* dstb = (char*)part + ((size_t)s * B + m0) * (D * 2);   // [s][b][d] bf16, 256 B/row
#pragma unroll
    for (int it = 0; it < 8; ++it) {
        const int off = (it * 256 + tid) * 16;                   // 0..32767, 16 B/lane
        uint4v v = *reinterpret_cast<const uint4v*>((char*)Sm + off);
        __builtin_nontemporal_store(v, reinterpret_cast<uint4v*>(dstb + off));
    }
}

// ---------------- stage 2: reduce splits + gathered cls dots + BCE + mean ----------------
__global__ __launch_bounds__(256)
void w2v_loss(const void* __restrict__ part, int nsplit, int part_bf16,
              const float* __restrict__ Wcls, const int* __restrict__ pathIdx,
              const float* __restrict__ codes, const float* __restrict__ mask,
              float* __restrict__ out) {
    const int lane = threadIdx.x & 63;
    const int wid  = threadIdx.x >> 6;
    const int b    = blockIdx.x * 4 + wid;     // one wave per sample

    // accumulate x[b][2*lane], x[b][2*lane+1] over splits
    float x0 = 0.f, x1 = 0.f;
    if (part_bf16) {
        const unsigned* pb = (const unsigned*)part;   // 64 uints per [s][b] row
        for (int s = 0; s < nsplit; ++s) {
            unsigned u = __builtin_nontemporal_load(&pb[((size_t)s * B + b) * 64 + lane]);
            x0 += __uint_as_float(u << 16);
            x1 += __uint_as_float(u & 0xFFFF0000u);
        }
    } else {
        const float* pf = (const float*)part;         // [B][D] fp32, pre-reduced
        const float2 v = *reinterpret_cast<const float2*>(&pf[(size_t)b * D + lane * 2]);
        x0 = v.x; x1 = v.y;
    }

    float lsum = 0.f, msum = 0.f;
#pragma unroll
    for (int p = 0; p < P; ++p) {
        int node = pathIdx[b * P + p];
        const float2 w = *reinterpret_cast<const float2*>(&Wcls[(size_t)node * D + lane * 2]);
        float d = x0 * w.x + x1 * w.y;
#pragma unroll
        for (int off = 1; off < 64; off <<= 1)
            d += __shfl_xor(d, off, 64);
        float t  = codes[b * P + p];
        float mm = mask[b * P + p];
        float loss = fmaxf(d, 0.f) - d * t + log1pf(__expf(-fabsf(d)));
        lsum += loss * mm;
        msum += mm;
    }
    float per = (msum > 0.f) ? (lsum / msum) : 0.f;

    __shared__ float wsum[4];
    if (lane == 0) wsum[wid] = per;
    __syncthreads();
    if (threadIdx.x == 0) {
        float ssum = wsum[0] + wsum[1] + wsum[2] + wsum[3];
        atomicAdd(out, ssum * (1.0f / (float)B));
    }
}

extern "C" void kernel_launch(void* const* d_in, const int* in_sizes, int n_in,
                              void* d_out, int out_size, void* d_ws, size_t ws_size,
                              hipStream_t stream) {
    const float* inputs = (const float*)d_in[0];   // [B,V]
    const float* W_emb  = (const float*)d_in[1];   // [D,V]
    const float* W_cls  = (const float*)d_in[2];   // [V,D]
    const int*   path   = (const int*)  d_in[3];   // [B,P]
    const float* codes  = (const float*)d_in[4];   // [B,P]
    const float* mask   = (const float*)d_in[5];   // [B,P]
    float* out = (float*)d_out;

    const size_t part_need = (size_t)NSPLIT * B * D * sizeof(unsigned short);  // ~29 MB bf16
    const int use_atomic = (ws_size < part_need) ? 1 : 0;
    const int nsplit_eff = use_atomic ? 1 : NSPLIT;

    if (use_atomic)
        hipMemsetAsync(d_ws, 0, (size_t)B * D * sizeof(float), stream);
    hipMemsetAsync(d_out, 0, sizeof(float), stream);

    w2v_gemm_splitk<<<dim3(NMT * NSPLIT), dim3(256), 0, stream>>>(inputs, W_emb, d_ws, use_atomic);
    w2v_loss<<<dim3(B / 4), dim3(256), 0, stream>>>(d_ws, nsplit_eff, use_atomic ? 0 : 1,
                                                    W_cls, path, codes, mask, out);
}

// Round 4
// 153.044 us; speedup vs baseline: 1.1448x; 1.1448x over previous
//
#include <hip/hip_runtime.h>
#include <hip/hip_bf16.h>

// Problem constants (from reference)
#define V 50000
#define D 128
#define B 2048
#define P 20

// Stage-1: x[B][D] = inputs[B][V] @ W_emb[D][V]^T, split-K
#define BM 256                  // 8 m-tiles
#define BK 64
#define NSPLIT 64               // KC=784: 63 full splits + tail 608
#define KC 784
#define NMT (B / BM)            // 8

typedef float  f32x4   __attribute__((ext_vector_type(4)));
typedef short  bf16x8  __attribute__((ext_vector_type(8)));
typedef unsigned int uint4v __attribute__((ext_vector_type(4)));

// truncating fp32->bf16 pack of two floats into one u32 (low = a, high = b)
__device__ __forceinline__ unsigned int pk2(float a, float b) {
    return (__float_as_uint(b) & 0xFFFF0000u) | (__float_as_uint(a) >> 16);
}
// RNE fp32->bf16
__device__ __forceinline__ unsigned short f2bf(float f) {
    unsigned int u = __float_as_uint(f);
    return (unsigned short)((u + 0x7FFFu + ((u >> 16) & 1u)) >> 16);
}
__device__ __forceinline__ bf16x8 pack8(f32x4 lo, f32x4 hi) {
    union { uint4v u; bf16x8 h; } r;
    r.u.x = pk2(lo[0], lo[1]); r.u.y = pk2(lo[2], lo[3]);
    r.u.z = pk2(hi[0], hi[1]); r.u.w = pk2(hi[2], hi[3]);
    return r.h;
}

// ---------------- pre-pass: W_emb fp32 -> bf16 (same [D][V] layout) ----------------
__global__ __launch_bounds__(256)
void w2v_wcast(const float* __restrict__ Wemb, unsigned* __restrict__ Wb) {
    const size_t t = (size_t)blockIdx.x * 256 + threadIdx.x;   // 8 elems/thread
    const size_t base = t * 8;
    if (base >= (size_t)D * V) return;                         // exact: 800000 threads
    const f32x4* src = reinterpret_cast<const f32x4*>(Wemb + base);
    f32x4 v0 = src[0], v1 = src[1];
    uint4v u;
    u.x = pk2(v0[0], v0[1]); u.y = pk2(v0[2], v0[3]);
    u.z = pk2(v1[0], v1[1]); u.w = pk2(v1[2], v1[3]);
    *reinterpret_cast<uint4v*>(Wb + base / 2) = u;
}

// ---------------- stage 1: split-K GEMM, A direct-to-frag, W via LDS ----------------
template<int WBF>
__global__ __launch_bounds__(512, 4)
void w2v_gemm(const float* __restrict__ Ain, const void* __restrict__ Wsrc,
              void* __restrict__ part, int use_atomic) {
    // smem: [0,16K) = W tile (128 d x 64 k bf16, XOR-swizzled); epilogue: 64 KB C tile
    __shared__ uint4v smem4[4096];
    char* smem = (char*)smem4;

    // XCD-aware mapping: the 8 m-blocks of a split share one XCD
    const int i   = blockIdx.x;            // 0..511
    const int xcd = i & 7;
    const int j   = i >> 3;                // 0..63
    const int s   = xcd * 8 + (j >> 3);    // 0..63
    const int mt  = j & 7;
    const int m0  = mt * BM;
    const int k0  = s * KC;
    const int k1  = (k0 + KC < V) ? (k0 + KC) : V;   // tail split: 608 = 19*32

    const int tid  = threadIdx.x;
    const int lane = tid & 63;
    const int wid  = tid >> 6;             // 0..7 -> rows [wid*32, wid*32+32)
    const int fr   = lane & 15;
    const int kg4  = lane >> 4;            // 0..3

    f32x4 acc[2][8] = {};

    const float* Arow0 = Ain + (size_t)(m0 + wid * 32 + fr) * V;   // m-frag 0
    const float* Arow1 = Arow0 + (size_t)16 * V;                   // m-frag 1

    for (int ks = k0; ks < k1; ks += BK) {
        // ---- stage W tile: 1024 slots x 16B, thread does slot tid, tid+512 ----
#pragma unroll
        for (int t2 = 0; t2 < 2; ++t2) {
            const int slot = tid + t2 * 512;
            const int d    = slot >> 3;
            const int c8   = slot & 7;
            const int kg   = ks + c8 * 8;
            uint4v u = {0u, 0u, 0u, 0u};
            if (kg < k1) {                 // 8-granular guard (k1 % 8 == 0)
                if (WBF) {
                    u = *reinterpret_cast<const uint4v*>(
                        (const unsigned short*)Wsrc + (size_t)d * V + kg);
                } else {
                    const f32x4* sp = reinterpret_cast<const f32x4*>(
                        (const float*)Wsrc + (size_t)d * V + kg);
                    f32x4 v0 = sp[0], v1 = sp[1];
                    u.x = pk2(v0[0], v0[1]); u.y = pk2(v0[2], v0[3]);
                    u.z = pk2(v1[0], v1[1]); u.w = pk2(v1[2], v1[3]);
                }
            }
            const unsigned dst = (unsigned)(d * 128) +
                (((unsigned)(c8 * 16)) ^ ((unsigned)(d & 7) << 4));
            *reinterpret_cast<uint4v*>(smem + dst) = u;
        }

        // ---- A fragments direct from global (issued before barrier) ----
        const int koff = ks + kg4 * 8;
        f32x4 a00l = {0,0,0,0}, a00h = {0,0,0,0}, a01l = {0,0,0,0}, a01h = {0,0,0,0};
        f32x4 a10l = {0,0,0,0}, a10h = {0,0,0,0}, a11l = {0,0,0,0}, a11h = {0,0,0,0};
        {   // kh = 0 always valid while ks < k1
            const f32x4* p0 = reinterpret_cast<const f32x4*>(Arow0 + koff);
            const f32x4* p1 = reinterpret_cast<const f32x4*>(Arow1 + koff);
            a00l = p0[0]; a00h = p0[1];
            a01l = p1[0]; a01h = p1[1];
        }
        const bool kh1v = (ks + 32 < k1);   // 32-granular (k1-k0 % 32 == 0)
        if (kh1v) {
            const f32x4* p0 = reinterpret_cast<const f32x4*>(Arow0 + koff + 32);
            const f32x4* p1 = reinterpret_cast<const f32x4*>(Arow1 + koff + 32);
            a10l = p0[0]; a10h = p0[1];
            a11l = p1[0]; a11h = p1[1];
        }
        __syncthreads();

        // ---- compute: kh=0 ----
        {
            const bf16x8 af0 = pack8(a00l, a00h);
            const bf16x8 af1 = pack8(a01l, a01h);
            const unsigned kb = (unsigned)kg4 << 4;
#pragma unroll
            for (int n = 0; n < 8; ++n) {
                const int r = n * 16 + fr;
                const bf16x8 wf = *reinterpret_cast<const bf16x8*>(
                    smem + r * 128 + (kb ^ ((unsigned)(r & 7) << 4)));
                acc[0][n] = __builtin_amdgcn_mfma_f32_16x16x32_bf16(af0, wf, acc[0][n], 0, 0, 0);
                acc[1][n] = __builtin_amdgcn_mfma_f32_16x16x32_bf16(af1, wf, acc[1][n], 0, 0, 0);
            }
        }
        // ---- compute: kh=32 ----
        if (kh1v) {
            const bf16x8 af0 = pack8(a10l, a10h);
            const bf16x8 af1 = pack8(a11l, a11h);
            const unsigned kb = 64u + ((unsigned)kg4 << 4);
#pragma unroll
            for (int n = 0; n < 8; ++n) {
                const int r = n * 16 + fr;
                const bf16x8 wf = *reinterpret_cast<const bf16x8*>(
                    smem + r * 128 + (kb ^ ((unsigned)(r & 7) << 4)));
                acc[0][n] = __builtin_amdgcn_mfma_f32_16x16x32_bf16(af0, wf, acc[0][n], 0, 0, 0);
                acc[1][n] = __builtin_amdgcn_mfma_f32_16x16x32_bf16(af1, wf, acc[1][n], 0, 0, 0);
            }
        }
        __syncthreads();
    }

    // ---- epilogue ----
    if (use_atomic) {
        float* outp = (float*)part;        // fp32 [B][D]
#pragma unroll
        for (int m = 0; m < 2; ++m) {
            const int r0 = m0 + wid * 32 + m * 16 + kg4 * 4;
#pragma unroll
            for (int n = 0; n < 8; ++n) {
                const int c0 = n * 16 + fr;
#pragma unroll
                for (int jj = 0; jj < 4; ++jj)
                    atomicAdd(&outp[(size_t)(r0 + jj) * D + c0], acc[m][n][jj]);
            }
        }
        return;
    }
    // bf16 C tile via LDS (smem now free), then coalesced 16B/lane stream-out
    unsigned short* Cs = (unsigned short*)smem;   // [256][128]
#pragma unroll
    for (int m = 0; m < 2; ++m) {
        const int r0 = wid * 32 + m * 16 + kg4 * 4;
#pragma unroll
        for (int n = 0; n < 8; ++n) {
            const int c0 = n * 16 + fr;
#pragma unroll
            for (int jj = 0; jj < 4; ++jj)
                Cs[(r0 + jj) * 128 + c0] = f2bf(acc[m][n][jj]);
        }
    }
    __syncthreads();
    char* dstb = (char*)part + ((size_t)s * B + m0) * (D * 2);   // [s][b][d] bf16
#pragma unroll
    for (int it = 0; it < 8; ++it) {
        const int off = (it * 512 + tid) * 16;                   // 0..65535
        uint4v v = *reinterpret_cast<const uint4v*>(smem + off);
        *reinterpret_cast<uint4v*>(dstb + off) = v;
    }
}

// ---------------- stage 2: reduce splits + gathered cls dots + BCE + mean ----------------
__global__ __launch_bounds__(256)
void w2v_loss(const void* __restrict__ part, int nsplit, int part_bf16,
              const float* __restrict__ Wcls, const int* __restrict__ pathIdx,
              const float* __restrict__ codes, const float* __restrict__ mask,
              float* __restrict__ out) {
    const int lane = threadIdx.x & 63;
    const int wid  = threadIdx.x >> 6;
    const int b    = blockIdx.x * 4 + wid;     // one wave per sample

    float x0 = 0.f, x1 = 0.f;                  // x[b][2*lane], x[b][2*lane+1]
    if (part_bf16) {
        const unsigned* pb = (const unsigned*)part;   // 64 u32 per [s][b] row
        for (int s = 0; s < nsplit; ++s) {
            unsigned u = pb[((size_t)s * B + b) * 64 + lane];
            x0 += __uint_as_float(u << 16);
            x1 += __uint_as_float(u & 0xFFFF0000u);
        }
    } else {
        const float* pf = (const float*)part;         // [B][D] fp32, pre-reduced
        const float2 v = *reinterpret_cast<const float2*>(&pf[(size_t)b * D + lane * 2]);
        x0 = v.x; x1 = v.y;
    }

    float lsum = 0.f, msum = 0.f;
#pragma unroll
    for (int p = 0; p < P; ++p) {
        int node = pathIdx[b * P + p];
        const float2 w = *reinterpret_cast<const float2*>(&Wcls[(size_t)node * D + lane * 2]);
        float d = x0 * w.x + x1 * w.y;
#pragma unroll
        for (int off = 1; off < 64; off <<= 1)
            d += __shfl_xor(d, off, 64);
        float t  = codes[b * P + p];
        float mm = mask[b * P + p];
        float loss = fmaxf(d, 0.f) - d * t + log1pf(__expf(-fabsf(d)));
        lsum += loss * mm;
        msum += mm;
    }
    float per = (msum > 0.f) ? (lsum / msum) : 0.f;

    __shared__ float wsum[4];
    if (lane == 0) wsum[wid] = per;
    __syncthreads();
    if (threadIdx.x == 0) {
        float ssum = wsum[0] + wsum[1] + wsum[2] + wsum[3];
        atomicAdd(out, ssum * (1.0f / (float)B));
    }
}

extern "C" void kernel_launch(void* const* d_in, const int* in_sizes, int n_in,
                              void* d_out, int out_size, void* d_ws, size_t ws_size,
                              hipStream_t stream) {
    const float* inputs = (const float*)d_in[0];   // [B,V]
    const float* W_emb  = (const float*)d_in[1];   // [D,V]
    const float* W_cls  = (const float*)d_in[2];   // [V,D]
    const int*   path   = (const int*)  d_in[3];   // [B,P]
    const float* codes  = (const float*)d_in[4];   // [B,P]
    const float* mask   = (const float*)d_in[5];   // [B,P]
    float* out = (float*)d_out;

    hipMemsetAsync(d_out, 0, sizeof(float), stream);

    const size_t wb_bytes  = (size_t)D * V * 2;                       // 12.8 MB bf16 W
    const size_t part_off  = (wb_bytes + 255) & ~(size_t)255;
    const size_t part_need = part_off + (size_t)NSPLIT * B * D * 2;   // ~46 MB

    if (ws_size >= part_need) {
        unsigned* Wb  = (unsigned*)d_ws;
        char* partp   = (char*)d_ws + part_off;
        w2v_wcast<<<dim3((D * V / 8 + 255) / 256), dim3(256), 0, stream>>>(W_emb, Wb);
        w2v_gemm<1><<<dim3(NMT * NSPLIT), dim3(512), 0, stream>>>(inputs, Wb, partp, 0);
        w2v_loss<<<dim3(B / 4), dim3(256), 0, stream>>>(partp, NSPLIT, 1,
                                                        W_cls, path, codes, mask, out);
    } else {
        hipMemsetAsync(d_ws, 0, (size_t)B * D * sizeof(float), stream);
        w2v_gemm<0><<<dim3(NMT * NSPLIT), dim3(512), 0, stream>>>(inputs, W_emb, d_ws, 1);
        w2v_loss<<<dim3(B / 4), dim3(256), 0, stream>>>(d_ws, 1, 0,
                                                        W_cls, path, codes, mask, out);
    }
}